// Round 1
// baseline (8992.352 us; speedup 1.0000x reference)
//
#include <hip/hip_runtime.h>

// RNN_73813307949430: 4-layer LSTM (H=50, T=10, F=5) + Dense(50) + Dense(1,sigmoid), B=131072.
// Round 0 baseline: fp32 vector (no fp32 MFMA on CDNA4), thread-per-element,
// per-layer kernels, h-sequence staged in d_ws [T][B][50] fp32, in-place across layers.
// z held in regs (2 unrolled halves of 25 units), h in LDS (runtime-k indexable),
// weights via wave-uniform scalar loads.

constexpr int H_  = 50;
constexpr int T_  = 10;
constexpr int F_  = 5;
constexpr int BLK = 128;
constexpr int NH  = 25;  // units per half

__device__ __forceinline__ float rcp_(float x) {
#if __has_builtin(__builtin_amdgcn_rcpf)
  return __builtin_amdgcn_rcpf(x);
#else
  return 1.0f / x;
#endif
}

__device__ __forceinline__ float sigmoid_(float x) {
  // x<<0: exp(-x)=inf -> rcp(inf)=0 ; x>>0: exp(-x)=0 -> 1. Safe unclamped.
  return rcp_(1.0f + __expf(-x));
}

__device__ __forceinline__ float tanhfast_(float x) {
  x = fminf(15.0f, fmaxf(-15.0f, x));  // keep exp finite
  float e = __expf(2.0f * x);
  return (e - 1.0f) * rcp_(e + 1.0f);
}

// Accumulate z[g*NH+j] = bias + x_t @ W + h @ U for one half (units BASE..BASE+NH).
// Weight/bias addresses are wave-uniform -> scalar loads. h comes from LDS column tid.
template <int FIN, int BASE, bool FIRST>
__device__ __forceinline__ void half_accum(const float* xt,
                                           const float* __restrict__ Wx,
                                           const float* __restrict__ Uh,
                                           const float* __restrict__ bias,
                                           const float* sh, int tid,
                                           float (&z)[4 * NH]) {
#pragma unroll
  for (int g = 0; g < 4; ++g)
#pragma unroll
    for (int j = 0; j < NH; ++j) z[g * NH + j] = bias[g * H_ + BASE + j];

  if constexpr (FIRST) {
    // FIN=5: fully unrolled, x_t preloadable into regs.
#pragma unroll
    for (int k = 0; k < FIN; ++k) {
      float v = xt[k];
      const float* wr = Wx + k * 4 * H_ + BASE;
#pragma unroll
      for (int g = 0; g < 4; ++g)
#pragma unroll
        for (int j = 0; j < NH; ++j)
          z[g * NH + j] = fmaf(v, wr[g * H_ + j], z[g * NH + j]);
    }
  } else {
    // FIN=50: runtime k loop, per-lane global load (L1-hot, 200B/thread row).
#pragma unroll 1
    for (int k = 0; k < FIN; ++k) {
      float v = xt[k];
      const float* wr = Wx + k * 4 * H_ + BASE;
#pragma unroll
      for (int g = 0; g < 4; ++g)
#pragma unroll
        for (int j = 0; j < NH; ++j)
          z[g * NH + j] = fmaf(v, wr[g * H_ + j], z[g * NH + j]);
    }
  }
  // recurrent part: h from LDS, runtime k
#pragma unroll 1
  for (int k = 0; k < H_; ++k) {
    float v = sh[k * BLK + tid];
    const float* ur = Uh + k * 4 * H_ + BASE;
#pragma unroll
    for (int g = 0; g < 4; ++g)
#pragma unroll
      for (int j = 0; j < NH; ++j)
        z[g * NH + j] = fmaf(v, ur[g * H_ + j], z[g * NH + j]);
  }
}

template <int BASE>
__device__ __forceinline__ void half_gate(float (&z)[4 * NH], float (&c)[H_],
                                          float (&hn)[NH]) {
#pragma unroll
  for (int j = 0; j < NH; ++j) {
    float i_ = sigmoid_(z[0 * NH + j]);
    float f_ = sigmoid_(z[1 * NH + j]);
    float g_ = tanhfast_(z[2 * NH + j]);
    float o_ = sigmoid_(z[3 * NH + j]);
    float cn = fmaf(f_, c[BASE + j], i_ * g_);
    c[BASE + j] = cn;
    hn[j] = o_ * tanhfast_(cn);
  }
}

// NOTE: xin/hout deliberately NOT __restrict__ — mid layers run in-place on d_ws.
template <int FIN, bool FIRST, bool LAST>
__global__ __launch_bounds__(BLK) void lstm_kernel(
    const float* xin, const float* __restrict__ Wx,
    const float* __restrict__ Uh, const float* __restrict__ bias, float* hout,
    int Bn, const float* __restrict__ Wd1, const float* __restrict__ bd1,
    const float* __restrict__ Wd2, const float* __restrict__ bd2, float* out) {
  __shared__ float sh[H_ * BLK];  // h state, column per thread (2-way bank alias = free)
  const int tid = threadIdx.x;
  const int b = blockIdx.x * BLK + tid;
  if (b >= Bn) return;

  float c[H_];
#pragma unroll
  for (int u = 0; u < H_; ++u) {
    c[u] = 0.0f;
    sh[u * BLK + tid] = 0.0f;
  }

#pragma unroll 1
  for (int t = 0; t < T_; ++t) {
    const float* xt = FIRST ? (xin + (size_t)b * (T_ * FIN) + t * FIN)
                            : (xin + ((size_t)t * Bn + b) * H_);
    float z[4 * NH];
    float hn0[NH], hn1[NH];
    half_accum<FIN, 0, FIRST>(xt, Wx, Uh, bias, sh, tid, z);
    half_gate<0>(z, c, hn0);
    half_accum<FIN, NH, FIRST>(xt, Wx, Uh, bias, sh, tid, z);
    half_gate<NH>(z, c, hn1);
    // All reads of row (t,b) are done; now safe to update LDS h and (in-place) global.
#pragma unroll
    for (int j = 0; j < NH; ++j) {
      sh[j * BLK + tid] = hn0[j];
      sh[(NH + j) * BLK + tid] = hn1[j];
    }
    if constexpr (!LAST) {
      float* orow = hout + ((size_t)t * Bn + b) * H_;
#pragma unroll
      for (int j = 0; j < NH; ++j) {
        orow[j] = hn0[j];
        orow[NH + j] = hn1[j];
      }
    }
  }

  if constexpr (LAST) {
    // Dense(50) + Dense(1, sigmoid) on final h (in sh columns).
    float d1[H_];
#pragma unroll
    for (int j = 0; j < H_; ++j) d1[j] = bd1[j];
#pragma unroll 1
    for (int k = 0; k < H_; ++k) {
      float v = sh[k * BLK + tid];
      const float* wr = Wd1 + k * H_;
#pragma unroll
      for (int j = 0; j < H_; ++j) d1[j] = fmaf(v, wr[j], d1[j]);
    }
    float acc = bd2[0];
#pragma unroll
    for (int j = 0; j < H_; ++j) acc = fmaf(d1[j], Wd2[j], acc);
    out[b] = sigmoid_(acc);
  }
}

extern "C" void kernel_launch(void* const* d_in, const int* in_sizes, int n_in,
                              void* d_out, int out_size, void* d_ws,
                              size_t ws_size, hipStream_t stream) {
  const float* x   = (const float*)d_in[0];
  const float* W1  = (const float*)d_in[1];
  const float* U1  = (const float*)d_in[2];
  const float* b1  = (const float*)d_in[3];
  const float* W2  = (const float*)d_in[4];
  const float* U2  = (const float*)d_in[5];
  const float* b2  = (const float*)d_in[6];
  const float* W3  = (const float*)d_in[7];
  const float* U3  = (const float*)d_in[8];
  const float* b3  = (const float*)d_in[9];
  const float* W4  = (const float*)d_in[10];
  const float* U4  = (const float*)d_in[11];
  const float* b4  = (const float*)d_in[12];
  const float* Wd1 = (const float*)d_in[13];
  const float* bd1 = (const float*)d_in[14];
  const float* Wd2 = (const float*)d_in[15];
  const float* bd2 = (const float*)d_in[16];

  const int Bn = in_sizes[0] / (T_ * F_);  // 131072
  float* buf = (float*)d_ws;               // [T][Bn][H] fp32 = 262 MB
  float* out = (float*)d_out;

  dim3 grid(Bn / BLK), blk(BLK);
  lstm_kernel<F_, true, false><<<grid, blk, 0, stream>>>(
      x, W1, U1, b1, buf, Bn, nullptr, nullptr, nullptr, nullptr, nullptr);
  lstm_kernel<H_, false, false><<<grid, blk, 0, stream>>>(
      buf, W2, U2, b2, buf, Bn, nullptr, nullptr, nullptr, nullptr, nullptr);
  lstm_kernel<H_, false, false><<<grid, blk, 0, stream>>>(
      buf, W3, U3, b3, buf, Bn, nullptr, nullptr, nullptr, nullptr, nullptr);
  lstm_kernel<H_, false, true><<<grid, blk, 0, stream>>>(
      buf, W4, U4, b4, nullptr, Bn, Wd1, bd1, Wd2, bd2, out);
}

// Round 2
// 650.965 us; speedup vs baseline: 13.8139x; 13.8139x over previous
//
#include <hip/hip_runtime.h>

// RNN_73813307949430: 4x LSTM(H=50,T=10,F=5) + Dense(50) + Dense(1,sigmoid), B=131072.
// Round 2: bf16 MFMA 16x16x32. One block = 64 batch rows, 4 waves; recurrence in-kernel.
// Weights pre-swizzled to B-fragment order, held in 64 VGPRs/wave (wave w owns unit
// columns w*16..w*16+15 of ALL 4 gates -> i,f,g,o co-resident per lane, gate math
// in-register). [X|H] tile in LDS (row pad +8 ushorts -> 2-way bank alias = free).
// h: C-layout regs -> LDS -> A-layout (m120 pattern). Dense1/2 collapsed to dot+bias.

typedef __attribute__((ext_vector_type(8))) short short8;
typedef __attribute__((ext_vector_type(4))) float floatx4;
typedef unsigned short u16;

constexpr int H_ = 50, T_ = 10, F_ = 5;
constexpr int MTILE = 64;     // batch rows per block
constexpr int BLKT = 256;     // 4 waves
constexpr int LROW = 136;     // LDS row stride (ushorts): 128 + 8 pad
constexpr float LOG2E = 1.4426950408889634f;

__device__ __forceinline__ float rcp_(float x) { return __builtin_amdgcn_rcpf(x); }
__device__ __forceinline__ float exp2_(float x) { return __builtin_amdgcn_exp2f(x); }
__device__ __forceinline__ float sig_(float x) { return rcp_(1.0f + exp2_(-LOG2E * x)); }
// tanh(x) = 1 - 2/(exp2(2*log2e*x)+1): saturates to +-1 at +-inf, no NaN, no clamp.
__device__ __forceinline__ float tanh_(float x) {
  return 1.0f - 2.0f * rcp_(1.0f + exp2_((2.0f * LOG2E) * x));
}

__device__ __forceinline__ u16 f2bf(float f) {
  union { float f; unsigned u; } v; v.f = f;
  unsigned r = v.u + 0x7FFFu + ((v.u >> 16) & 1u);  // RNE
  return (u16)(r >> 16);
}
__device__ __forceinline__ float bf2f(u16 s) {
  union { unsigned u; float f; } v; v.u = ((unsigned)s) << 16;
  return v.f;
}

// ---- prep: swizzle weights into per-lane B-fragment order, fold dense layers ----
// Wpp layout: [layer][kt][gate][wave][lane][8] bf16 (32768/layer).
// B-frag convention (16x16x32): B[k = (lane>>4)*8 + j][n = lane&15].
__global__ void prep_kernel(
    const float* W1, const float* U1, const float* b1, const float* W2,
    const float* U2, const float* b2, const float* W3, const float* U3,
    const float* b3, const float* W4, const float* U4, const float* b4,
    const float* Wd1, const float* bd1, const float* Wd2, const float* bd2,
    u16* Wpp, float* biasP, float* vdense) {
  int idx = blockIdx.x * blockDim.x + threadIdx.x;
  const float* Wt[4] = {W1, W2, W3, W4};
  const float* Ut[4] = {U1, U2, U3, U4};
  const float* bt[4] = {b1, b2, b3, b4};
  const int fin[4] = {F_, H_, H_, H_};
  if (idx < 4 * 32768) {
    int l = idx >> 15, r = idx & 32767;
    int j = r & 7, lane = (r >> 3) & 63, w = (r >> 9) & 3, gI = (r >> 11) & 3,
        kt = r >> 13;
    int row = kt * 32 + (lane >> 4) * 8 + j;  // K position (0..127)
    int u = w * 16 + (lane & 15);             // unit (0..63)
    float val = 0.0f;
    if (u < H_) {
      if (row < 64) {
        if (row < fin[l]) val = Wt[l][row * 200 + gI * H_ + u];
      } else {
        int rr = row - 64;
        if (rr < H_) val = Ut[l][rr * 200 + gI * H_ + u];
      }
    }
    Wpp[idx] = f2bf(val);
  } else if (idx < 4 * 32768 + 1024) {
    int r = idx - 4 * 32768;
    int l = r >> 8, q = r & 255, gI = q >> 6, u = q & 63;
    biasP[r] = (u < H_) ? bt[l][gI * H_ + u] : 0.0f;
  } else if (idx < 4 * 32768 + 1024 + 51) {
    int u = idx - (4 * 32768 + 1024);
    if (u < H_) {  // v = Wd1 @ Wd2  (Dense(50) is linear -> collapse)
      float s = 0.0f;
      for (int n = 0; n < H_; ++n) s += Wd1[u * H_ + n] * Wd2[n];
      vdense[u] = s;
    } else {  // beta = bd1 . Wd2 + bd2
      float s = bd2[0];
      for (int n = 0; n < H_; ++n) s += bd1[n] * Wd2[n];
      vdense[50] = s;
    }
  }
}

// ---- main LSTM layer kernel ----
template <bool FIRST, bool LAST>
__global__ __launch_bounds__(BLKT, 2) void lstm_mfma(
    const float* __restrict__ x0, u16* hbuf, const u16* __restrict__ Wpp,
    const float* __restrict__ biasP, int Bn, const float* __restrict__ vdense,
    float* __restrict__ out) {
  __shared__ u16 A[MTILE * LROW];  // [64 rows][K=128 +8 pad]: cols 0..63 X, 64..127 H
  const int tid = threadIdx.x;
  const int w = tid >> 6, lane = tid & 63;
  const int np = lane & 15, quad = lane >> 4;
  const int b0 = blockIdx.x * MTILE;
  const int u = w * 16 + np;  // unit this lane owns (>=50 -> zero weights, harmless)

  // B fragments: wave w's 16-col slice of each gate, all K. 64 VGPRs, loaded once.
  short8 bfr[4][4];  // [kt][gate]
#pragma unroll
  for (int kt = 0; kt < 4; ++kt)
#pragma unroll
    for (int gI = 0; gI < 4; ++gI)
      bfr[kt][gI] = *(const short8*)&Wpp[(((kt * 4 + gI) * 4 + w) * 64 + lane) * 8];

  float bv[4];
#pragma unroll
  for (int gI = 0; gI < 4; ++gI) bv[gI] = biasP[gI * 64 + u];

  for (int i = tid; i < MTILE * LROW; i += BLKT) A[i] = 0;  // zero X-pad + initial H

  float cst[16];  // c state: rows mt*16 + quad*4 + reg, unit u
#pragma unroll
  for (int i = 0; i < 16; ++i) cst[i] = 0.0f;

  __syncthreads();

#pragma unroll 1
  for (int t = 0; t < T_; ++t) {
    // stage X_t -> LDS cols 0..63
    if constexpr (FIRST) {
      for (int e = tid; e < MTILE * F_; e += BLKT) {
        int row = e / F_, k = e - row * F_;
        A[row * LROW + k] = f2bf(x0[(size_t)(b0 + row) * (T_ * F_) + t * F_ + k]);
      }
    } else {
      const u16* src = hbuf + ((size_t)t * Bn + b0) * 64;
#pragma unroll
      for (int e2 = 0; e2 < 2; ++e2) {
        int e = tid + e2 * BLKT;
        int row = e >> 3, cc = e & 7;
        *(short8*)&A[row * LROW + cc * 8] = *(const short8*)&src[row * 64 + cc * 8];
      }
    }
    __syncthreads();

    floatx4 acc[4][4];  // [mt][gate], bias-initialized
#pragma unroll
    for (int mt = 0; mt < 4; ++mt)
#pragma unroll
      for (int gI = 0; gI < 4; ++gI)
        acc[mt][gI] = floatx4{bv[gI], bv[gI], bv[gI], bv[gI]};

#pragma unroll
    for (int kt = 0; kt < 4; ++kt) {
#pragma unroll
      for (int mt = 0; mt < 4; ++mt) {
        // A-frag: A[m = lane&15][k = quad*8 + j]
        short8 af = *(const short8*)&A[(mt * 16 + np) * LROW + kt * 32 + quad * 8];
#pragma unroll
        for (int gI = 0; gI < 4; ++gI)
          acc[mt][gI] = __builtin_amdgcn_mfma_f32_16x16x32_bf16(
              af, bfr[kt][gI], acc[mt][gI], 0, 0, 0);
      }
    }
    __syncthreads();

    // gates in-register (i,f,g,o co-resident per lane); h -> LDS H-cols
#pragma unroll
    for (int mt = 0; mt < 4; ++mt) {
#pragma unroll
      for (int reg = 0; reg < 4; ++reg) {
        float i_ = sig_(acc[mt][0][reg]);
        float f_ = sig_(acc[mt][1][reg]);
        float g_ = tanh_(acc[mt][2][reg]);
        float o_ = sig_(acc[mt][3][reg]);
        float cn = f_ * cst[mt * 4 + reg] + i_ * g_;
        cst[mt * 4 + reg] = cn;
        float h = o_ * tanh_(cn);
        int row = mt * 16 + quad * 4 + reg;  // C/D: col=lane&15, row=quad*4+reg
        A[row * LROW + 64 + u] = f2bf(h);
      }
    }
    if constexpr (!LAST) {
      __syncthreads();  // h visible to copier threads
      u16* dst = hbuf + ((size_t)t * Bn + b0) * 64;
#pragma unroll
      for (int e2 = 0; e2 < 2; ++e2) {
        int e = tid + e2 * BLKT;
        int row = e >> 3, cc = e & 7;
        *(short8*)&dst[row * 64 + cc * 8] = *(const short8*)&A[row * LROW + 64 + cc * 8];
      }
    }
    // next iteration's sync (after X staging) makes H-writes visible to MFMA
  }

  if constexpr (LAST) {
    __syncthreads();
    if (tid < MTILE) {  // fused Dense(50)+Dense(1): out = sigmoid(h . v + beta)
      float s = vdense[50];
      for (int k = 0; k < H_; ++k) s += bf2f(A[tid * LROW + 64 + k]) * vdense[k];
      out[b0 + tid] = sig_(s);
    }
  }
}

extern "C" void kernel_launch(void* const* d_in, const int* in_sizes, int n_in,
                              void* d_out, int out_size, void* d_ws,
                              size_t ws_size, hipStream_t stream) {
  const float* x = (const float*)d_in[0];
  const float* W1 = (const float*)d_in[1];
  const float* U1 = (const float*)d_in[2];
  const float* b1 = (const float*)d_in[3];
  const float* W2 = (const float*)d_in[4];
  const float* U2 = (const float*)d_in[5];
  const float* b2 = (const float*)d_in[6];
  const float* W3 = (const float*)d_in[7];
  const float* U3 = (const float*)d_in[8];
  const float* b3 = (const float*)d_in[9];
  const float* W4 = (const float*)d_in[10];
  const float* U4 = (const float*)d_in[11];
  const float* b4 = (const float*)d_in[12];
  const float* Wd1 = (const float*)d_in[13];
  const float* bd1 = (const float*)d_in[14];
  const float* Wd2 = (const float*)d_in[15];
  const float* bd2 = (const float*)d_in[16];

  const int Bn = in_sizes[0] / (T_ * F_);  // 131072
  char* ws = (char*)d_ws;
  u16* hbuf = (u16*)ws;                                   // [T][Bn][64] bf16 = 160 MB
  size_t off = (size_t)T_ * Bn * 64 * sizeof(u16);        // 167,772,160
  u16* Wpp = (u16*)(ws + off);                            // 4 x 32768 bf16
  float* biasP = (float*)(ws + off + 262144);             // 4 x 256 f32
  float* vdense = (float*)(ws + off + 262144 + 4096);     // 51 f32
  float* out = (float*)d_out;

  prep_kernel<<<(4 * 32768 + 1024 + 51 + 255) / 256, 256, 0, stream>>>(
      W1, U1, b1, W2, U2, b2, W3, U3, b3, W4, U4, b4, Wd1, bd1, Wd2, bd2, Wpp,
      biasP, vdense);

  dim3 grid(Bn / MTILE), blk(BLKT);
  lstm_mfma<true, false><<<grid, blk, 0, stream>>>(
      x, hbuf, Wpp + 0 * 32768, biasP + 0 * 256, Bn, vdense, nullptr);
  lstm_mfma<false, false><<<grid, blk, 0, stream>>>(
      nullptr, hbuf, Wpp + 1 * 32768, biasP + 1 * 256, Bn, vdense, nullptr);
  lstm_mfma<false, false><<<grid, blk, 0, stream>>>(
      nullptr, hbuf, Wpp + 2 * 32768, biasP + 2 * 256, Bn, vdense, nullptr);
  lstm_mfma<false, true><<<grid, blk, 0, stream>>>(
      nullptr, hbuf, Wpp + 3 * 32768, biasP + 3 * 256, Bn, vdense, out);
}

// Round 4
// 571.211 us; speedup vs baseline: 15.7426x; 1.1396x over previous
//
#include <hip/hip_runtime.h>

// RNN_73813307949430: 4x LSTM(H=50,T=10,F=5) + Dense(50) + Dense(1,sigmoid), B=131072.
// Round 3b: fragment-contiguous LDS A-layout (conflict-free ds_read_b128), chunked
// global hbuf (coalesced b128 staging, wave-local copy-out -> 2 barriers/t),
// prescaled weights (log2e folded), shared-rcp + v_pk_f32 pairwise gate math,
// packed bf16 convert (manual RNE; __builtin_bit_cast of __hip_bfloat162 doesn't
// compile), next-t staging prefetch.
//
// LDS A = 1024 chunks of 16B: chunk(mt,kt,quad,rr) = ((mt*4+kt)*4+quad)*16+rr
// holds A[row=mt*16+rr][k=kt*32+quad*8+j], j=0..7. MFMA A-frag read for (mt,kt):
// lane(np,quad) reads chunk base+lane -> consecutive 16B per lane = conflict-free.
// k 0..63 = X (input), k 64..127 = H (recurrent). Unit u maps to k=64+u.

typedef __attribute__((ext_vector_type(8))) short short8;
typedef __attribute__((ext_vector_type(4))) float floatx4;
typedef __attribute__((ext_vector_type(2))) float float2v;
typedef unsigned short u16;
typedef unsigned int u32;

constexpr int H_ = 50, T_ = 10, F_ = 5;
constexpr int MTILE = 64;   // batch rows per block
constexpr int BLKT = 256;   // 4 waves
constexpr float LOG2E = 1.4426950408889634f;

__device__ __forceinline__ float rcp_(float x) { return __builtin_amdgcn_rcpf(x); }
__device__ __forceinline__ float exp2_(float x) { return __builtin_amdgcn_exp2f(x); }
__device__ __forceinline__ float sig_nat(float x) {
  return rcp_(1.0f + exp2_(-LOG2E * x));
}

__device__ __forceinline__ u16 f2bf(float f) {
  union { float f; unsigned u; } v; v.f = f;
  unsigned r = v.u + 0x7FFFu + ((v.u >> 16) & 1u);  // RNE
  return (u16)(r >> 16);
}
__device__ __forceinline__ float bf2f(u16 s) {
  union { unsigned u; float f; } v; v.u = ((unsigned)s) << 16;
  return v.f;
}
__device__ __forceinline__ unsigned pk_bf16(float a, float b) {
  return (unsigned)f2bf(a) | ((unsigned)f2bf(b) << 16);
}

// ---- prep: swizzle weights into B-fragment order with activation prescale ----
// Wpp[layer][kt][gate][wave][lane][8]; B[k=(lane>>4)*8+j][n=lane&15].
// Gates i,f,o scaled by -log2e (sig = rcp(1+exp2(z))); gate g by +2*log2e
// (tanh = 1-2*rcp(1+exp2(z))). Bias scaled identically.
__global__ void prep_kernel(
    const float* W1, const float* U1, const float* b1, const float* W2,
    const float* U2, const float* b2, const float* W3, const float* U3,
    const float* b3, const float* W4, const float* U4, const float* b4,
    const float* Wd1, const float* bd1, const float* Wd2, const float* bd2,
    u16* Wpp, float* biasP, float* vdense) {
  int idx = blockIdx.x * blockDim.x + threadIdx.x;
  const float* Wt[4] = {W1, W2, W3, W4};
  const float* Ut[4] = {U1, U2, U3, U4};
  const float* bt[4] = {b1, b2, b3, b4};
  const int fin[4] = {F_, H_, H_, H_};
  if (idx < 4 * 32768) {
    int l = idx >> 15, r = idx & 32767;
    int j = r & 7, lane = (r >> 3) & 63, w = (r >> 9) & 3, gI = (r >> 11) & 3,
        kt = r >> 13;
    int row = kt * 32 + (lane >> 4) * 8 + j;  // K position (0..127)
    int u = w * 16 + (lane & 15);             // unit (0..63)
    float val = 0.0f;
    if (u < H_) {
      if (row < 64) {
        if (row < fin[l]) val = Wt[l][row * 200 + gI * H_ + u];
      } else {
        int rr = row - 64;
        if (rr < H_) val = Ut[l][rr * 200 + gI * H_ + u];
      }
    }
    val *= (gI == 2) ? (2.0f * LOG2E) : (-LOG2E);
    Wpp[idx] = f2bf(val);
  } else if (idx < 4 * 32768 + 1024) {
    int r = idx - 4 * 32768;
    int l = r >> 8, q = r & 255, gI = q >> 6, u = q & 63;
    float val = (u < H_) ? bt[l][gI * H_ + u] : 0.0f;
    biasP[r] = val * ((gI == 2) ? (2.0f * LOG2E) : (-LOG2E));
  } else if (idx < 4 * 32768 + 1024 + 51) {
    int u = idx - (4 * 32768 + 1024);
    if (u < H_) {  // v = Wd1 @ Wd2 (Dense(50) linear -> collapse)
      float s = 0.0f;
      for (int n = 0; n < H_; ++n) s += Wd1[u * H_ + n] * Wd2[n];
      vdense[u] = s;
    } else {
      float s = bd2[0];
      for (int n = 0; n < H_; ++n) s += bd1[n] * Wd2[n];
      vdense[50] = s;
    }
  }
}

// ---- main LSTM layer kernel ----
template <bool FIRST, bool LAST>
__global__ __launch_bounds__(BLKT, 2) void lstm_mfma(
    const float* __restrict__ x0, u16* hbuf, const u16* __restrict__ Wpp,
    const float* __restrict__ biasP, int nblk, const float* __restrict__ vdense,
    float* __restrict__ out) {
  __shared__ __align__(16) u16 A[8192];  // 1024 x 16B chunks
  const int tid = threadIdx.x;
  const int w = tid >> 6, lane = tid & 63;
  const int np = lane & 15, quad = lane >> 4;
  const int blk = blockIdx.x;
  const int b0 = blk * MTILE;
  const int u = w * 16 + np;

  // B fragments (prescaled), 64 VGPRs, loaded once (L2-resident).
  short8 bfr[4][4];
#pragma unroll
  for (int kt = 0; kt < 4; ++kt)
#pragma unroll
    for (int gI = 0; gI < 4; ++gI)
      bfr[kt][gI] = *(const short8*)&Wpp[(((kt * 4 + gI) * 4 + w) * 64 + lane) * 8];

  float bv[4];
#pragma unroll
  for (int gI = 0; gI < 4; ++gI) bv[gI] = biasP[gI * 64 + u];

  for (int i = tid; i < 4096; i += BLKT) ((u32*)A)[i] = 0;  // X pad + initial H

  float2v cst[8];  // c state pairs: rows mt*16+quad*4+{2p,2p+1}, unit u
#pragma unroll
  for (int i = 0; i < 8; ++i) cst[i] = float2v{0.0f, 0.0f};

  // initial staging prefetch (mid/last layers)
  short8 rx0, rx1;
  if constexpr (!FIRST) {
    const u16* s0 = hbuf + ((size_t)0 * nblk + blk) * 4096;
    rx0 = *(const short8*)(s0 + (size_t)tid * 8);
    rx1 = *(const short8*)(s0 + (size_t)(tid + 256) * 8);
  }

  const int kt_u = 2 + (w >> 1);  // h-write chunk coords for this lane
  const int cbase = ((kt_u * 4 + ((w & 1) * 2 + (np >> 3))) * 16 + quad * 4) * 8 + (np & 7);

  __syncthreads();

#pragma unroll 1
  for (int t = 0; t < T_; ++t) {
    // ---- stage X_t ----
    if constexpr (!FIRST) {
      {
        int hc = tid, mt = hc >> 7, kk = (hc >> 6) & 1, rest = hc & 63;
        *(short8*)&A[((mt * 4 + kk) * 64 + rest) * 8] = rx0;
      }
      {
        int hc = tid + 256, mt = hc >> 7, kk = (hc >> 6) & 1, rest = hc & 63;
        *(short8*)&A[((mt * 4 + kk) * 64 + rest) * 8] = rx1;
      }
      if (t + 1 < T_) {  // prefetch next t; in flight across MFMA+epilogue
        const u16* s1 = hbuf + ((size_t)(t + 1) * nblk + blk) * 4096;
        rx0 = *(const short8*)(s1 + (size_t)tid * 8);
        rx1 = *(const short8*)(s1 + (size_t)(tid + 256) * 8);
      }
    } else {
      for (int e = tid; e < MTILE * F_; e += BLKT) {
        int row = e / F_, k = e - row * F_;
        int mt = row >> 4, rr = row & 15;
        A[(mt * 256 + rr) * 8 + k] =
            f2bf(x0[(size_t)(b0 + row) * (T_ * F_) + t * F_ + k]);
      }
    }
    __syncthreads();  // (A) X+H visible

    floatx4 acc[4][4];
#pragma unroll
    for (int mt = 0; mt < 4; ++mt)
#pragma unroll
      for (int gI = 0; gI < 4; ++gI)
        acc[mt][gI] = floatx4{bv[gI], bv[gI], bv[gI], bv[gI]};

#pragma unroll
    for (int kt = 0; kt < 4; ++kt) {
      if (FIRST && kt == 1) continue;  // k 32..63 all-zero in layer 1
#pragma unroll
      for (int mt = 0; mt < 4; ++mt) {
        short8 af = *(const short8*)&A[(((mt * 4 + kt) * 4 + quad) * 16 + np) * 8];
#pragma unroll
        for (int gI = 0; gI < 4; ++gI)
          acc[mt][gI] = __builtin_amdgcn_mfma_f32_16x16x32_bf16(
              af, bfr[kt][gI], acc[mt][gI], 0, 0, 0);
      }
    }
    __syncthreads();  // (B) all MFMA reads of X/H done

    // ---- gates: pairwise (v_pk_f32), shared reciprocals, prescaled z ----
#pragma unroll
    for (int mt = 0; mt < 4; ++mt) {
#pragma unroll
      for (int p = 0; p < 2; ++p) {
        float2v di = {exp2_(acc[mt][0][2 * p]), exp2_(acc[mt][0][2 * p + 1])};
        float2v df = {exp2_(acc[mt][1][2 * p]), exp2_(acc[mt][1][2 * p + 1])};
        float2v dg = {exp2_(acc[mt][2][2 * p]), exp2_(acc[mt][2][2 * p + 1])};
        float2v do_ = {exp2_(acc[mt][3][2 * p]), exp2_(acc[mt][3][2 * p + 1])};
        di += 1.0f; df += 1.0f; dg += 1.0f; do_ += 1.0f;
        float2v m1 = di * df, m2 = do_ * dg;
        float2v P = m1 * m2;                       // di*df*do*dg
        float Rs = rcp_(P.x * P.y);                // one rcp for 8 factors
        float2v R = {Rs * P.y, Rs * P.x};
        float2v i_ = (df * m2) * R;                // = 1/di
        float2v f_ = (di * m2) * R;                // = 1/df
        float2v o_ = (m1 * dg) * R;                // = 1/do
        float2v g_ = 1.0f - 2.0f * ((m1 * do_) * R);  // = 1-2/dg
        float2v cn = f_ * cst[mt * 2 + p] + i_ * g_;
        cst[mt * 2 + p] = cn;
        float2v s = cn * (2.0f * LOG2E);
        float2v dc = {exp2_(s.x), exp2_(s.y)};
        dc += 1.0f;
        float Rc = rcp_(dc.x * dc.y);
        float2v tc = 1.0f - 2.0f * float2v{Rc * dc.y, Rc * dc.x};
        float2v h = o_ * tc;
        unsigned pk = pk_bf16(h.x, h.y);
        int a0 = cbase + mt * 2048 + (2 * p) * 8;  // rows quad*4+2p, +1
        A[a0] = (u16)pk;
        A[a0 + 8] = (u16)(pk >> 16);
      }
    }

    // ---- copy-out h_t: wave reads ONLY its own chunks -> no barrier needed ----
    if constexpr (!LAST) {
      u16* dst = hbuf + ((size_t)t * nblk + blk) * 4096;
#pragma unroll
      for (int rep = 0; rep < 2; ++rep) {
        int e = lane + 64 * rep;
        int mt = e >> 5, rem = e & 31, qp = rem >> 4, rr = rem & 15;
        int quad_u = (w & 1) * 2 + qp;
        int ldsc = ((mt * 4 + kt_u) * 4 + quad_u) * 16 + rr;
        int hch = ((mt * 2 + (w >> 1)) * 4 + quad_u) * 16 + rr;
        *(short8*)&dst[(size_t)hch * 8] = *(const short8*)&A[ldsc * 8];
      }
    }
  }

  if constexpr (LAST) {
    __syncthreads();
    if (tid < MTILE) {  // out = sigmoid(h . (Wd1@Wd2) + beta)
      int mt = tid >> 4, rr = tid & 15;
      float s = vdense[50];
      for (int k = 0; k < H_; ++k) {
        int ktu = 2 + (k >> 5), qd = (k & 31) >> 3, j = k & 7;
        s += bf2f(A[(((mt * 4 + ktu) * 4 + qd) * 16 + rr) * 8 + j]) * vdense[k];
      }
      out[b0 + tid] = sig_nat(s);
    }
  }
}

extern "C" void kernel_launch(void* const* d_in, const int* in_sizes, int n_in,
                              void* d_out, int out_size, void* d_ws,
                              size_t ws_size, hipStream_t stream) {
  const float* x = (const float*)d_in[0];
  const float* W1 = (const float*)d_in[1];
  const float* U1 = (const float*)d_in[2];
  const float* b1 = (const float*)d_in[3];
  const float* W2 = (const float*)d_in[4];
  const float* U2 = (const float*)d_in[5];
  const float* b2 = (const float*)d_in[6];
  const float* W3 = (const float*)d_in[7];
  const float* U3 = (const float*)d_in[8];
  const float* b3 = (const float*)d_in[9];
  const float* W4 = (const float*)d_in[10];
  const float* U4 = (const float*)d_in[11];
  const float* b4 = (const float*)d_in[12];
  const float* Wd1 = (const float*)d_in[13];
  const float* bd1 = (const float*)d_in[14];
  const float* Wd2 = (const float*)d_in[15];
  const float* bd2 = (const float*)d_in[16];

  const int Bn = in_sizes[0] / (T_ * F_);  // 131072
  const int nblk = Bn / MTILE;             // 2048
  char* ws = (char*)d_ws;
  u16* hbuf = (u16*)ws;  // [T][nblk][512 chunks][8] bf16 = 168 MB
  size_t off = (size_t)T_ * nblk * 4096 * sizeof(u16);
  u16* Wpp = (u16*)(ws + off);                         // 4 x 32768 bf16
  float* biasP = (float*)(ws + off + 262144);          // 4 x 256 f32
  float* vdense = (float*)(ws + off + 262144 + 4096);  // 51 f32
  float* out = (float*)d_out;

  prep_kernel<<<(4 * 32768 + 1024 + 51 + 255) / 256, 256, 0, stream>>>(
      W1, U1, b1, W2, U2, b2, W3, U3, b3, W4, U4, b4, Wd1, bd1, Wd2, bd2, Wpp,
      biasP, vdense);

  dim3 grid(nblk), blkd(BLKT);
  lstm_mfma<true, false><<<grid, blkd, 0, stream>>>(
      x, hbuf, Wpp + 0 * 32768, biasP + 0 * 256, nblk, vdense, nullptr);
  lstm_mfma<false, false><<<grid, blkd, 0, stream>>>(
      nullptr, hbuf, Wpp + 1 * 32768, biasP + 1 * 256, nblk, vdense, nullptr);
  lstm_mfma<false, false><<<grid, blkd, 0, stream>>>(
      nullptr, hbuf, Wpp + 2 * 32768, biasP + 2 * 256, nblk, vdense, nullptr);
  lstm_mfma<false, true><<<grid, blkd, 0, stream>>>(
      nullptr, hbuf, Wpp + 3 * 32768, biasP + 3 * 256, nblk, vdense, out);
}